// Round 2
// baseline (527.416 us; speedup 1.0000x reference)
//
#include <hip/hip_runtime.h>
#include <stdint.h>

#define GN 2048
#define EN 512
#define BN 16

__device__ __forceinline__ float bf2f(unsigned short u) {
    return __uint_as_float(((unsigned int)u) << 16);
}
__device__ __forceinline__ unsigned short f2bf(float f) {
    unsigned int u = __float_as_uint(f);
    u += 0x7fffu + ((u >> 16) & 1u);   // RNE
    return (unsigned short)(u >> 16);
}
__device__ __forceinline__ float lrelu(float v) { return v > 0.f ? v : 0.01f * v; }

union U16x8 { uint4 v; unsigned short s[8]; };

template<bool ISBF>
__device__ __forceinline__ float ldf(const void* p, size_t i) {
    if (ISBF) return bf2f(((const unsigned short*)p)[i]);
    return ((const float*)p)[i];
}

template<bool ISBF>
__device__ __forceinline__ void ld8(const void* p, size_t off, float* v) {
    if (ISBF) {
        U16x8 u; u.v = *(const uint4*)((const unsigned short*)p + off);
        #pragma unroll
        for (int i = 0; i < 8; i++) v[i] = bf2f(u.s[i]);
    } else {
        const float* q = (const float*)p + off;
        const float4 a = *(const float4*)q;
        const float4 b = *(const float4*)(q + 4);
        v[0]=a.x; v[1]=a.y; v[2]=a.z; v[3]=a.w;
        v[4]=b.x; v[5]=b.y; v[6]=b.z; v[7]=b.w;
    }
}

template<bool ISBF>
__device__ __forceinline__ void st8(void* p, size_t off, const float* v) {
    if (ISBF) {
        U16x8 u;
        #pragma unroll
        for (int i = 0; i < 8; i++) u.s[i] = f2bf(v[i]);
        *(uint4*)((unsigned short*)p + off) = u.v;
    } else {
        float* q = (float*)p + off;
        *(float4*)q       = make_float4(v[0], v[1], v[2], v[3]);
        *(float4*)(q + 4) = make_float4(v[4], v[5], v[6], v[7]);
    }
}

// ---------------------------------------------------------------------------
// SNIFF: decide whether float tensors are bf16 or fp32 at runtime.
// embMat ~ N(0,1). If bf16: low u16 of each u32 word is a bf16 with exponent
// field in ~[117,128]. If fp32: those bits are mantissa noise (~10% pass).
// ---------------------------------------------------------------------------
__global__ void sniff_k(const unsigned int* __restrict__ emb, int* __restrict__ flag) {
    const int t = threadIdx.x;
    const unsigned int w = emb[t];
    const int e = (w >> 7) & 0xFF;
    const int ok = (e >= 108 && e <= 134) ? 1 : 0;
    const unsigned long long m = __ballot(ok);
    if (t == 0) flag[0] = (__popcll(m) >= 40) ? 1 : 0;
}

// ---------------------------------------------------------------------------
// P1: xbin floats [B*G]; q0,q1,k0,k1 (4 x E matvecs); w_eff[g'] = sum_g fcCox[g]*fc1_w[g,g']
// ---------------------------------------------------------------------------
template<bool ISBF>
__device__ __forceinline__ void pre1_body(
    const int* __restrict__ datax, const void* emb, const void* Wq, const void* Wk,
    const void* fc1w, const void* fcCox,
    float* __restrict__ xf, float* __restrict__ qk, float* __restrict__ weff)
{
    int id = blockIdx.x * 256 + threadIdx.x;
    if (id < BN * GN) {
        xf[id] = (datax[id] != 0) ? 1.f : 0.f;
    } else if (id < BN * GN + 4 * EN) {
        int j = id - BN * GN;
        int which = j >> 9;             // 0:q0 1:q1 2:k0 3:k1
        int f = j & (EN - 1);
        const void* W = (which < 2) ? Wq : Wk;
        const size_t eoff = (size_t)(which & 1) * EN;
        float acc = 0.f;
        for (int ei = 0; ei < EN; ei++)
            acc += ldf<ISBF>(W, (size_t)f * EN + ei) * ldf<ISBF>(emb, eoff + ei);
        qk[j] = acc;
    } else if (id < BN * GN + 4 * EN + GN) {
        int gp = id - (BN * GN + 4 * EN);
        float acc = 0.f;
        for (int gg = 0; gg < GN; gg++)
            acc += ldf<ISBF>(fcCox, gg) * ldf<ISBF>(fc1w, (size_t)gg * GN + gp);
        weff[gp] = acc;
    }
}

__global__ __launch_bounds__(256) void pre1_k(
    const int* datax, const void* emb, const void* Wq, const void* Wk,
    const void* fc1w, const void* fcCox,
    float* xf, float* qk, float* weff, const int* flag)
{
    if (flag[0]) pre1_body<true>(datax, emb, Wq, Wk, fc1w, fcCox, xf, qk, weff);
    else         pre1_body<false>(datax, emb, Wq, Wk, fc1w, fcCox, xf, qk, weff);
}

// ---------------------------------------------------------------------------
// P2: s00,s01,s10,s11 = q_a . k_c ; c = sum fc1_b[g]*fcCox[g]
// ---------------------------------------------------------------------------
template<bool ISBF>
__device__ __forceinline__ void pre2_body(
    const float* __restrict__ qk, const void* fc1b, const void* fcCox,
    float* __restrict__ sv, float* __restrict__ cptr)
{
    int t = threadIdx.x;
    float a[5] = {0.f, 0.f, 0.f, 0.f, 0.f};
    for (int e = t; e < EN; e += 256) {
        float q0 = qk[e], q1 = qk[EN + e];
        float K0 = qk[2 * EN + e], K1 = qk[3 * EN + e];
        a[0] += q0 * K0; a[1] += q0 * K1; a[2] += q1 * K0; a[3] += q1 * K1;
    }
    for (int gg = t; gg < GN; gg += 256)
        a[4] += ldf<ISBF>(fc1b, gg) * ldf<ISBF>(fcCox, gg);
    for (int o = 32; o >= 1; o >>= 1)
        #pragma unroll
        for (int j = 0; j < 5; j++) a[j] += __shfl_xor(a[j], o);
    __shared__ float red[4][5];
    int wid = t >> 6, lane = t & 63;
    if (lane == 0)
        for (int j = 0; j < 5; j++) red[wid][j] = a[j];
    __syncthreads();
    if (t == 0) {
        for (int j = 0; j < 4; j++)
            sv[j] = red[0][j] + red[1][j] + red[2][j] + red[3][j];
        cptr[0] = red[0][4] + red[1][4] + red[2][4] + red[3][4];
    }
}

__global__ __launch_bounds__(256) void pre2_k(
    const float* qk, const void* fc1b, const void* fcCox,
    float* sv, float* cptr, const int* flag)
{
    if (flag[0]) pre2_body<true>(qk, fc1b, fcCox, sv, cptr);
    else         pre2_body<false>(qk, fc1b, fcCox, sv, cptr);
}

// ---------------------------------------------------------------------------
// MAIN: one block per g-row.
// ---------------------------------------------------------------------------
template<bool ISBF>
__device__ __forceinline__ void attn_body(
    const void* k1, const void* k2, const void* k3,
    const void* sp, const void* cen, const void* pad,
    const float* __restrict__ xf, const float* __restrict__ sv,
    float* __restrict__ attn2, void* d_out)
{
    const int g = blockIdx.x;
    const int t = threadIdx.x;
    const int h0 = t << 3;
    const size_t roff = (size_t)g * GN + h0;

    const float lr3 = lrelu(ldf<ISBF>(k3, 0));

    float a1[8], a2[8], vsp[8], vcn[8], vpd[8];
    ld8<ISBF>(k1, roff, a1);
    ld8<ISBF>(k2, roff, a2);
    ld8<ISBF>(sp, roff, vsp);
    ld8<ISBF>(cen, roff, vcn);
    ld8<ISBF>(pad, roff, vpd);

    float bias8[8];
    float lmax = -3.4e38f;
    #pragma unroll
    for (int i = 0; i < 8; i++) {
        float b = lrelu(a1[i]) * vsp[i] + lrelu(a2[i]) * vcn[i] + lr3 * vpd[i];
        bias8[i] = b;
        lmax = fmaxf(lmax, b);
    }
    for (int o = 32; o >= 1; o >>= 1) lmax = fmaxf(lmax, __shfl_xor(lmax, o));

    __shared__ float smax[4];
    __shared__ float red[4][32];
    const int wid = t >> 6, lane = t & 63;
    if (lane == 0) smax[wid] = lmax;
    __syncthreads();
    const float Mg = fmaxf(fmaxf(smax[0], smax[1]), fmaxf(smax[2], smax[3]));

    float E8[8];
    #pragma unroll
    for (int i = 0; i < 8; i++) E8[i] = __expf(bias8[i] - Mg);

    float s0l[BN], s1l[BN];
    unsigned int maskv[BN];
    #pragma unroll
    for (int b = 0; b < BN; b++) {
        const float4 xa = *(const float4*)(xf + b * GN + h0);
        const float4 xb = *(const float4*)(xf + b * GN + h0 + 4);
        const float xv[8] = {xa.x, xa.y, xa.z, xa.w, xb.x, xb.y, xb.z, xb.w};
        float acc0 = 0.f, acc1 = 0.f;
        unsigned int mk = 0;
        #pragma unroll
        for (int i = 0; i < 8; i++) {
            const bool on = (xv[i] != 0.f);
            acc1 += on ? E8[i] : 0.f;
            acc0 += on ? 0.f : E8[i];
            mk |= (on ? 1u : 0u) << i;
        }
        s0l[b] = acc0; s1l[b] = acc1; maskv[b] = mk;
    }
    for (int o = 32; o >= 1; o >>= 1) {
        #pragma unroll
        for (int b = 0; b < BN; b++) {
            s0l[b] += __shfl_xor(s0l[b], o);
            s1l[b] += __shfl_xor(s1l[b], o);
        }
    }
    if (lane == 0) {
        #pragma unroll
        for (int b = 0; b < BN; b++) {
            red[wid][b] = s0l[b];
            red[wid][BN + b] = s1l[b];
        }
    }
    __syncthreads();

    const float s00 = sv[0], s01 = sv[1], s10 = sv[2], s11 = sv[3];

    #pragma unroll
    for (int b = 0; b < BN; b++) {
        const float S0 = fmaxf(red[0][b] + red[1][b] + red[2][b] + red[3][b], 1e-35f);
        const float S1 = fmaxf(red[0][BN + b] + red[1][BN + b] + red[2][BN + b] + red[3][BN + b], 1e-35f);

        const float av = xf[b * GN + g];
        const bool on = (av != 0.f);
        const float sa0 = on ? s10 : s00;
        const float sa1 = on ? s11 : s01;
        const float d = (sa0 + __logf(S0)) - (sa1 + __logf(S1));
        const float attnv = 1.f / (1.f + __expf(d));
        if (t == 0) attn2[b * GN + g] = av + attnv;

        const float ds = sa1 - sa0;
        const unsigned int mk = maskv[b];
        float ov[8];
        #pragma unroll
        for (int i = 0; i < 8; i++)
            ov[i] = bias8[i] + sa0 + (((mk >> i) & 1u) ? ds : 0.f);
        // outputs concatenated: [0..15]=output, then attn_weights_origin
        st8<ISBF>(d_out, (size_t)BN + ((size_t)b * GN + g) * GN + h0, ov);
    }
}

__global__ __launch_bounds__(256) void attn_k(
    const void* k1, const void* k2, const void* k3,
    const void* sp, const void* cen, const void* pad,
    const float* xf, const float* sv, float* attn2, void* d_out, const int* flag)
{
    if (flag[0]) attn_body<true>(k1, k2, k3, sp, cen, pad, xf, sv, attn2, d_out);
    else         attn_body<false>(k1, k2, k3, sp, cen, pad, xf, sv, attn2, d_out);
}

// ---------------------------------------------------------------------------
// FIN: out[b] = c + sum_g attn2[b,g] * w_eff[g]
// ---------------------------------------------------------------------------
template<bool ISBF>
__device__ __forceinline__ void final_body(
    const float* __restrict__ attn2, const float* __restrict__ weff,
    const float* __restrict__ cptr, void* d_out)
{
    const int b = blockIdx.x, t = threadIdx.x;
    const int h0 = t << 3;
    const float4 a0 = *(const float4*)(attn2 + b * GN + h0);
    const float4 a1 = *(const float4*)(attn2 + b * GN + h0 + 4);
    const float4 w0 = *(const float4*)(weff + h0);
    const float4 w1 = *(const float4*)(weff + h0 + 4);
    float acc = a0.x * w0.x + a0.y * w0.y + a0.z * w0.z + a0.w * w0.w
              + a1.x * w1.x + a1.y * w1.y + a1.z * w1.z + a1.w * w1.w;
    for (int o = 32; o >= 1; o >>= 1) acc += __shfl_xor(acc, o);
    __shared__ float red[4];
    const int wid = t >> 6, lane = t & 63;
    if (lane == 0) red[wid] = acc;
    __syncthreads();
    if (t == 0) {
        const float val = cptr[0] + red[0] + red[1] + red[2] + red[3];
        if (ISBF) ((unsigned short*)d_out)[b] = f2bf(val);
        else      ((float*)d_out)[b] = val;
    }
}

__global__ __launch_bounds__(256) void final_k(
    const float* attn2, const float* weff, const float* cptr,
    void* d_out, const int* flag)
{
    if (flag[0]) final_body<true>(attn2, weff, cptr, d_out);
    else         final_body<false>(attn2, weff, cptr, d_out);
}

extern "C" void kernel_launch(void* const* d_in, const int* in_sizes, int n_in,
                              void* d_out, int out_size, void* d_ws, size_t ws_size,
                              hipStream_t stream) {
    const int*  datax = (const int*)d_in[0];
    const void* emb   = d_in[1];
    const void* Wq    = d_in[2];
    const void* Wk    = d_in[3];
    const void* k1    = d_in[4];
    const void* k2    = d_in[5];
    const void* k3    = d_in[6];
    const void* sp    = d_in[7];
    const void* cen   = d_in[8];
    const void* pad   = d_in[9];
    const void* fc1w  = d_in[10];
    const void* fc1b  = d_in[11];
    const void* fcCox = d_in[12];

    float* ws    = (float*)d_ws;
    float* qk    = ws;              // 2048 floats
    float* sv    = ws + 2048;       // 4
    float* cptr  = ws + 2052;       // 1
    float* xf    = ws + 2056;       // 32768 (byte offset 8224, 16B aligned)
    float* weff  = ws + 34824;      // 2048
    float* attn2 = ws + 36872;      // 32768
    int*   flag  = (int*)(ws + 69640); // 1 int

    sniff_k<<<1, 64, 0, stream>>>((const unsigned int*)emb, flag);
    pre1_k<<<144, 256, 0, stream>>>(datax, emb, Wq, Wk, fc1w, fcCox, xf, qk, weff, flag);
    pre2_k<<<1, 256, 0, stream>>>(qk, fc1b, fcCox, sv, cptr, flag);
    attn_k<<<GN, 256, 0, stream>>>(k1, k2, k3, sp, cen, pad, xf, sv, attn2, d_out, flag);
    final_k<<<BN, 256, 0, stream>>>(attn2, weff, cptr, d_out, flag);
}

// Round 3
// 396.951 us; speedup vs baseline: 1.3287x; 1.3287x over previous
//
#include <hip/hip_runtime.h>
#include <stdint.h>

#define GN 2048
#define EN 512
#define BN 16

__device__ __forceinline__ float bf2f(unsigned short u) {
    return __uint_as_float(((unsigned int)u) << 16);
}
__device__ __forceinline__ unsigned short f2bf(float f) {
    unsigned int u = __float_as_uint(f);
    u += 0x7fffu + ((u >> 16) & 1u);   // RNE
    return (unsigned short)(u >> 16);
}
__device__ __forceinline__ float lrelu(float v) { return v > 0.f ? v : 0.01f * v; }

union U16x8 { uint4 v; unsigned short s[8]; };

template<bool ISBF>
__device__ __forceinline__ float ldf(const void* p, size_t i) {
    if (ISBF) return bf2f(((const unsigned short*)p)[i]);
    return ((const float*)p)[i];
}

template<bool ISBF>
__device__ __forceinline__ void ld8(const void* p, size_t off, float* v) {
    if (ISBF) {
        U16x8 u; u.v = *(const uint4*)((const unsigned short*)p + off);
        #pragma unroll
        for (int i = 0; i < 8; i++) v[i] = bf2f(u.s[i]);
    } else {
        const float* q = (const float*)p + off;
        const float4 a = *(const float4*)q;
        const float4 b = *(const float4*)(q + 4);
        v[0]=a.x; v[1]=a.y; v[2]=a.z; v[3]=a.w;
        v[4]=b.x; v[5]=b.y; v[6]=b.z; v[7]=b.w;
    }
}

template<bool ISBF>
__device__ __forceinline__ void st8(void* p, size_t off, const float* v) {
    if (ISBF) {
        U16x8 u;
        #pragma unroll
        for (int i = 0; i < 8; i++) u.s[i] = f2bf(v[i]);
        *(uint4*)((unsigned short*)p + off) = u.v;
    } else {
        float* q = (float*)p + off;
        *(float4*)q       = make_float4(v[0], v[1], v[2], v[3]);
        *(float4*)(q + 4) = make_float4(v[4], v[5], v[6], v[7]);
    }
}

// ---------------------------------------------------------------------------
// SNIFF: bf16 vs fp32 runtime detection on embMat (~N(0,1)).
// ---------------------------------------------------------------------------
__global__ void sniff_k(const unsigned int* __restrict__ emb, int* __restrict__ flag) {
    const int t = threadIdx.x;
    const unsigned int w = emb[t];
    const int e = (w >> 7) & 0xFF;
    const int ok = (e >= 108 && e <= 134) ? 1 : 0;
    const unsigned long long m = __ballot(ok);
    if (t == 0) flag[0] = (__popcll(m) >= 40) ? 1 : 0;
}

// ---------------------------------------------------------------------------
// SETUP (grid 400):
//  blocks [0,16):    xpackT[t][b] bytes: bit i = (datax[b, 8t+i] != 0)
//  blocks [16,272):  qk — one wave per (W in {Wq,Wk}, f): dots vs emb rows 0,1
//  blocks [272,400): weff partials — block pb covers rows [16pb,16pb+16)
// ---------------------------------------------------------------------------
template<bool ISBF>
__device__ __forceinline__ void setup_body(
    const int* __restrict__ datax, const void* emb, const void* Wq, const void* Wk,
    const void* fc1w, const void* fcCox,
    unsigned char* __restrict__ xpackT, float* __restrict__ qk,
    float* __restrict__ partials)
{
    const int blk = blockIdx.x;
    const int t = threadIdx.x;

    if (blk < 16) {
        const int b = blk;
        unsigned int byte = 0;
        const int base = b * GN + t * 8;
        #pragma unroll
        for (int i = 0; i < 8; i++)
            byte |= (datax[base + i] != 0 ? 1u : 0u) << i;
        xpackT[t * 16 + b] = (unsigned char)byte;
    } else if (blk < 272) {
        const int iw = (blk - 16) * 4 + (t >> 6);   // 0..1023
        const int lane = t & 63;
        const void* W = (iw < 512) ? Wq : Wk;
        const int f = iw & 511;
        float w8[8], e0[8], e1[8];
        ld8<ISBF>(W, (size_t)f * EN + lane * 8, w8);
        ld8<ISBF>(emb, (size_t)lane * 8, e0);
        ld8<ISBF>(emb, (size_t)EN + lane * 8, e1);
        float d0 = 0.f, d1 = 0.f;
        #pragma unroll
        for (int i = 0; i < 8; i++) { d0 += w8[i] * e0[i]; d1 += w8[i] * e1[i]; }
        for (int o = 32; o >= 1; o >>= 1) {
            d0 += __shfl_xor(d0, o);
            d1 += __shfl_xor(d1, o);
        }
        if (lane == 0) {
            const int base = (iw < 512) ? 0 : 1024;
            qk[base + f] = d0;          // dot with emb row 0
            qk[base + 512 + f] = d1;    // dot with emb row 1
        }
    } else {
        const int pb = blk - 272;                    // 0..127
        float acc[8] = {0.f,0.f,0.f,0.f,0.f,0.f,0.f,0.f};
        for (int r = 0; r < 16; r++) {
            const int g = pb * 16 + r;
            const float c = ldf<ISBF>(fcCox, g);
            float w8[8];
            ld8<ISBF>(fc1w, (size_t)g * GN + t * 8, w8);
            #pragma unroll
            for (int i = 0; i < 8; i++) acc[i] += c * w8[i];
        }
        float* q = partials + (size_t)pb * GN + t * 8;
        *(float4*)q       = make_float4(acc[0], acc[1], acc[2], acc[3]);
        *(float4*)(q + 4) = make_float4(acc[4], acc[5], acc[6], acc[7]);
    }
}

__global__ __launch_bounds__(256) void setup_k(
    const int* datax, const void* emb, const void* Wq, const void* Wk,
    const void* fc1w, const void* fcCox,
    unsigned char* xpackT, float* qk, float* partials, const int* flag)
{
    if (flag[0]) setup_body<true>(datax, emb, Wq, Wk, fc1w, fcCox, xpackT, qk, partials);
    else         setup_body<false>(datax, emb, Wq, Wk, fc1w, fcCox, xpackT, qk, partials);
}

// ---------------------------------------------------------------------------
// PRE2 (grid 9): block 0: s00..s11 + bias-dot constant; blocks 1..8: weff reduce
// ---------------------------------------------------------------------------
template<bool ISBF>
__device__ __forceinline__ void pre2_body(
    const float* __restrict__ qk, const void* fc1b, const void* fcCox,
    const float* __restrict__ partials,
    float* __restrict__ sv, float* __restrict__ cptr, float* __restrict__ weff)
{
    const int t = threadIdx.x;
    if (blockIdx.x > 0) {
        const int c = (blockIdx.x - 1) * 256 + t;
        float acc = 0.f;
        for (int r = 0; r < 128; r++)
            acc += partials[(size_t)r * GN + c];
        weff[c] = acc;
        return;
    }
    float a[5] = {0.f, 0.f, 0.f, 0.f, 0.f};
    for (int e = t; e < EN; e += 256) {
        float q0 = qk[e], q1 = qk[EN + e];
        float K0 = qk[2 * EN + e], K1 = qk[3 * EN + e];
        a[0] += q0 * K0; a[1] += q0 * K1; a[2] += q1 * K0; a[3] += q1 * K1;
    }
    for (int gg = t; gg < GN; gg += 256)
        a[4] += ldf<ISBF>(fc1b, gg) * ldf<ISBF>(fcCox, gg);
    for (int o = 32; o >= 1; o >>= 1)
        #pragma unroll
        for (int j = 0; j < 5; j++) a[j] += __shfl_xor(a[j], o);
    __shared__ float red[4][5];
    int wid = t >> 6, lane = t & 63;
    if (lane == 0)
        for (int j = 0; j < 5; j++) red[wid][j] = a[j];
    __syncthreads();
    if (t == 0) {
        for (int j = 0; j < 4; j++)
            sv[j] = red[0][j] + red[1][j] + red[2][j] + red[3][j];
        cptr[0] = red[0][4] + red[1][4] + red[2][4] + red[3][4];
    }
}

__global__ __launch_bounds__(256) void pre2_k(
    const float* qk, const void* fc1b, const void* fcCox, const float* partials,
    float* sv, float* cptr, float* weff, const int* flag)
{
    if (flag[0]) pre2_body<true>(qk, fc1b, fcCox, partials, sv, cptr, weff);
    else         pre2_body<false>(qk, fc1b, fcCox, partials, sv, cptr, weff);
}

// ---------------------------------------------------------------------------
// MAIN: one block per g-row.
// ---------------------------------------------------------------------------
template<bool ISBF>
__device__ __forceinline__ void attn_body(
    const void* k1, const void* k2, const void* k3,
    const void* sp, const void* cen, const void* pad,
    const unsigned char* __restrict__ xpackT, const float* __restrict__ sv,
    float* __restrict__ attn2, void* d_out)
{
    const int g = blockIdx.x;
    const int t = threadIdx.x;
    const int h0 = t << 3;
    const size_t roff = (size_t)g * GN + h0;

    const float lr3 = lrelu(ldf<ISBF>(k3, 0));

    float a1[8], a2[8], vsp[8], vcn[8], vpd[8];
    ld8<ISBF>(k1, roff, a1);
    ld8<ISBF>(k2, roff, a2);
    ld8<ISBF>(sp, roff, vsp);
    ld8<ISBF>(cen, roff, vcn);
    ld8<ISBF>(pad, roff, vpd);

    float bias8[8];
    float lmax = -3.4e38f;
    #pragma unroll
    for (int i = 0; i < 8; i++) {
        float b = lrelu(a1[i]) * vsp[i] + lrelu(a2[i]) * vcn[i] + lr3 * vpd[i];
        bias8[i] = b;
        lmax = fmaxf(lmax, b);
    }
    for (int o = 32; o >= 1; o >>= 1) lmax = fmaxf(lmax, __shfl_xor(lmax, o));

    __shared__ float smax[4];
    __shared__ float redT[4];
    __shared__ float red[4][BN];
    const int wid = t >> 6, lane = t & 63;
    if (lane == 0) smax[wid] = lmax;
    __syncthreads();
    const float Mg = fmaxf(fmaxf(smax[0], smax[1]), fmaxf(smax[2], smax[3]));

    float E8[8];
    float Tl = 0.f;
    #pragma unroll
    for (int i = 0; i < 8; i++) { E8[i] = __expf(bias8[i] - Mg); Tl += E8[i]; }

    // packed membership bits: byte b of this uint4 = bits for batch b, h0..h0+7
    const uint4 pk = *(const uint4*)(xpackT + (size_t)t * 16);
    const unsigned char* pb = (const unsigned char*)&pk;

    float s1l[BN];
    #pragma unroll
    for (int b = 0; b < BN; b++) {
        const unsigned int mk = pb[b];
        float acc1 = 0.f;
        #pragma unroll
        for (int i = 0; i < 8; i++)
            acc1 += ((mk >> i) & 1u) ? E8[i] : 0.f;
        s1l[b] = acc1;
    }
    for (int o = 32; o >= 1; o >>= 1) {
        Tl += __shfl_xor(Tl, o);
        #pragma unroll
        for (int b = 0; b < BN; b++) s1l[b] += __shfl_xor(s1l[b], o);
    }
    if (lane == 0) {
        redT[wid] = Tl;
        #pragma unroll
        for (int b = 0; b < BN; b++) red[wid][b] = s1l[b];
    }
    __syncthreads();
    const float Tg = redT[0] + redT[1] + redT[2] + redT[3];

    const float s00 = sv[0], s01 = sv[1], s10 = sv[2], s11 = sv[3];
    // membership bits of column g for all 16 batches:
    const uint4 gk = *(const uint4*)(xpackT + (size_t)(g >> 3) * 16);
    const unsigned char* gb = (const unsigned char*)&gk;
    const int gbit = g & 7;

    #pragma unroll
    for (int b = 0; b < BN; b++) {
        const float S1 = fmaxf(red[0][b] + red[1][b] + red[2][b] + red[3][b], 1e-30f);
        const float S0 = fmaxf(Tg - S1, 1e-30f);

        const bool on = ((gb[b] >> gbit) & 1u) != 0u;
        const float sa0 = on ? s10 : s00;
        const float sa1 = on ? s11 : s01;
        const float d = (sa0 + __logf(S0)) - (sa1 + __logf(S1));
        const float attnv = 1.f / (1.f + __expf(d));
        if (t == 0) attn2[b * GN + g] = (on ? 1.f : 0.f) + attnv;

        const float ds = sa1 - sa0;
        const unsigned int mk = pb[b];
        float ov[8];
        #pragma unroll
        for (int i = 0; i < 8; i++)
            ov[i] = bias8[i] + sa0 + (((mk >> i) & 1u) ? ds : 0.f);
        st8<ISBF>(d_out, (size_t)BN + ((size_t)b * GN + g) * GN + h0, ov);
    }
}

__global__ __launch_bounds__(256) void attn_k(
    const void* k1, const void* k2, const void* k3,
    const void* sp, const void* cen, const void* pad,
    const unsigned char* xpackT, const float* sv, float* attn2,
    void* d_out, const int* flag)
{
    if (flag[0]) attn_body<true>(k1, k2, k3, sp, cen, pad, xpackT, sv, attn2, d_out);
    else         attn_body<false>(k1, k2, k3, sp, cen, pad, xpackT, sv, attn2, d_out);
}

// ---------------------------------------------------------------------------
// FIN: out[b] = c + sum_g attn2[b,g] * w_eff[g]
// ---------------------------------------------------------------------------
template<bool ISBF>
__device__ __forceinline__ void final_body(
    const float* __restrict__ attn2, const float* __restrict__ weff,
    const float* __restrict__ cptr, void* d_out)
{
    const int b = blockIdx.x, t = threadIdx.x;
    const int h0 = t << 3;
    const float4 a0 = *(const float4*)(attn2 + b * GN + h0);
    const float4 a1 = *(const float4*)(attn2 + b * GN + h0 + 4);
    const float4 w0 = *(const float4*)(weff + h0);
    const float4 w1 = *(const float4*)(weff + h0 + 4);
    float acc = a0.x * w0.x + a0.y * w0.y + a0.z * w0.z + a0.w * w0.w
              + a1.x * w1.x + a1.y * w1.y + a1.z * w1.z + a1.w * w1.w;
    for (int o = 32; o >= 1; o >>= 1) acc += __shfl_xor(acc, o);
    __shared__ float red[4];
    const int wid = t >> 6, lane = t & 63;
    if (lane == 0) red[wid] = acc;
    __syncthreads();
    if (t == 0) {
        const float val = cptr[0] + red[0] + red[1] + red[2] + red[3];
        if (ISBF) ((unsigned short*)d_out)[b] = f2bf(val);
        else      ((float*)d_out)[b] = val;
    }
}

__global__ __launch_bounds__(256) void final_k(
    const float* attn2, const float* weff, const float* cptr,
    void* d_out, const int* flag)
{
    if (flag[0]) final_body<true>(attn2, weff, cptr, d_out);
    else         final_body<false>(attn2, weff, cptr, d_out);
}

extern "C" void kernel_launch(void* const* d_in, const int* in_sizes, int n_in,
                              void* d_out, int out_size, void* d_ws, size_t ws_size,
                              hipStream_t stream) {
    const int*  datax = (const int*)d_in[0];
    const void* emb   = d_in[1];
    const void* Wq    = d_in[2];
    const void* Wk    = d_in[3];
    const void* k1    = d_in[4];
    const void* k2    = d_in[5];
    const void* k3    = d_in[6];
    const void* sp    = d_in[7];
    const void* cen   = d_in[8];
    const void* pad   = d_in[9];
    const void* fc1w  = d_in[10];
    const void* fc1b  = d_in[11];
    const void* fcCox = d_in[12];

    float* ws       = (float*)d_ws;
    float* qk       = ws;                   // 2048 floats
    float* sv       = ws + 2048;            // 4
    float* cptr     = ws + 2052;            // 1
    float* weff     = ws + 2056;            // 2048
    float* attn2    = ws + 4104;            // 32768
    float* partials = ws + 36872;           // 128*2048 = 262144
    unsigned char* xpackT = (unsigned char*)(ws + 299016); // 4096 B
    int*   flag     = (int*)(ws + 300040);  // 1 int

    sniff_k<<<1, 64, 0, stream>>>((const unsigned int*)emb, flag);
    setup_k<<<400, 256, 0, stream>>>(datax, emb, Wq, Wk, fc1w, fcCox,
                                     xpackT, qk, partials, flag);
    pre2_k<<<9, 256, 0, stream>>>(qk, fc1b, fcCox, partials, sv, cptr, weff, flag);
    attn_k<<<GN, 256, 0, stream>>>(k1, k2, k3, sp, cen, pad, xpackT, sv, attn2, d_out, flag);
    final_k<<<BN, 256, 0, stream>>>(attn2, weff, cptr, d_out, flag);
}